// Round 9
// baseline (218.898 us; speedup 1.0000x reference)
//
#include <hip/hip_runtime.h>
#include <hip/hip_bf16.h>

#define B_ROWS 65536
#define NA 128
#define D_OUT 1024
#define VBS 128
#define NCHUNK (B_ROWS / VBS)   // 512

typedef __attribute__((ext_vector_type(8))) short bf16x8s;
typedef __attribute__((ext_vector_type(4))) float f32x4;
typedef __attribute__((ext_vector_type(4))) unsigned short u16x4;
typedef __attribute__((ext_vector_type(8))) unsigned short u16x8;

static __device__ __forceinline__ short f2bf(float f) {
    unsigned u = __builtin_bit_cast(unsigned, f);
    u = u + 0x7FFFu + ((u >> 16) & 1u);   // round-to-nearest-even to bf16
    return (short)(u >> 16);
}
static __device__ __forceinline__ float bf2f(unsigned short h) {
    unsigned u = ((unsigned)h) << 16;
    return __builtin_bit_cast(float, u);
}
// packed RNE f32->bf16 pair: 1 VALU op for 2 elements (dst.lo=bf16(a), dst.hi=bf16(b))
static __device__ __forceinline__ unsigned cvt_pk_bf16(float a, float b) {
    unsigned r;
    asm("v_cvt_pk_bf16_f32 %0, %1, %2" : "=v"(r) : "v"(a), "v"(b));
    return r;
}

// One block per virtual batch (chunk): 128 threads, one per feature.
__global__ void gbn_stats_kernel(const float* __restrict__ a,
                                 const float* __restrict__ gamma,
                                 const float* __restrict__ beta,
                                 float* __restrict__ ss) {
    int c = blockIdx.x;
    int j = threadIdx.x;            // feature 0..127
    const float* p = a + (size_t)c * (VBS * NA) + j;
    float s = 0.f, s2 = 0.f;
#pragma unroll 8
    for (int r = 0; r < VBS; ++r) {
        float v = p[r * NA];
        s += v; s2 += v * v;
    }
    float mean = s * (1.f / VBS);
    float var  = fmaxf(s2 * (1.f / VBS) - mean * mean, 0.f);   // biased var
    float sc = gamma[j] * rsqrtf(var + 1e-5f);
    float sh = beta[j] - mean * sc;
    float2* o = (float2*)ss + (c * NA + j);
    *o = make_float2(sc, sh);
}

// Pack W (f32 [1024][128]) into bf16 fragment-contiguous chunks:
// chunk c = ((wave*4 + ks)*16 + nf)*64 + lane, lane=(g*16+q), holding
// W[wave*256 + nf*16 + q][ks*32 + g*8 .. +8].
__global__ void wpack_kernel(const float* __restrict__ W, u16x8* __restrict__ Wp) {
    int c = blockIdx.x * 256 + threadIdx.x;   // 16384 chunks
    int lane = c & 63;
    int nf   = (c >> 6) & 15;
    int ks   = (c >> 10) & 3;
    int wv   = (c >> 12) & 3;
    int g = lane >> 4, q = lane & 15;
    const float* src = W + (size_t)(wv * 256 + nf * 16 + q) * NA + ks * 32 + g * 8;
    u16x8 h;
#pragma unroll
    for (int i = 0; i < 8; ++i) h[i] = (unsigned short)f2bf(src[i]);
    Wp[c] = h;
}

// One block per 16 rows; wave w owns cols [w*256, +256). Swapped-operand MFMA:
// thread (g,q) holds y[r0+q][w*256+nf*16+4g+r]. Epilogue: *prior (registers),
// bf16 LDS transpose (padded layout), then per-wave sparsemax threshold via
// bracketed bisection with segment-exact termination. NOTE the reference's
// sign convention: its tau = (1-cum_k)/k = -tau_std, so out = relu(x + tau_std).
__global__ __launch_bounds__(256, 2) void fused_kernel(
    const float* __restrict__ a,
    const float* __restrict__ prior,
    const float* __restrict__ ss,
    const u16x8* __restrict__ Wp,
    float* __restrict__ out) {

    const int tid  = threadIdx.x;
    const int wave = tid >> 6;        // 0..3  (N block of 256)
    const int lane = tid & 63;
    const int g    = lane >> 4;       // 0..3
    const int q    = lane & 15;       // output row within tile

    const int r0    = blockIdx.x * 16;
    const int chunk = r0 >> 7;

    // ---- prefetch prior into registers (HBM latency overlaps GEMM) ----
    float4 pr[16];
    {
        const float* pb = prior + (size_t)(r0 + q) * D_OUT + wave * 256 + 4 * g;
#pragma unroll
        for (int nf = 0; nf < 16; ++nf) pr[nf] = *(const float4*)(pb + nf * 16);
    }

    f32x4 acc[16];
#pragma unroll
    for (int i = 0; i < 16; ++i) acc[i] = (f32x4){0.f, 0.f, 0.f, 0.f};

    const float* ssb = ss + (size_t)chunk * NA * 2;

    // ---- GEMM: y[16 x 1024] = GBN(a_tile)[16 x 128] * W^T (operands swapped) ----
#pragma unroll
    for (int ks = 0; ks < 4; ++ks) {
        const int k0 = ks * 32 + g * 8;
        const float4* ap = (const float4*)(a + (size_t)(r0 + q) * NA + k0);
        float4 v0 = ap[0], v1 = ap[1];
        const float4* sp = (const float4*)(ssb + k0 * 2);   // interleaved (sc,sh)
        float4 s0 = sp[0], s1 = sp[1], s2 = sp[2], s3 = sp[3];
        int4 ai;
        ai.x = (int)cvt_pk_bf16(v0.x * s0.x + s0.y, v0.y * s0.z + s0.w);
        ai.y = (int)cvt_pk_bf16(v0.z * s1.x + s1.y, v0.w * s1.z + s1.w);
        ai.z = (int)cvt_pk_bf16(v1.x * s2.x + s2.y, v1.y * s2.z + s2.w);
        ai.w = (int)cvt_pk_bf16(v1.z * s3.x + s3.y, v1.w * s3.z + s3.w);
        bf16x8s af = __builtin_bit_cast(bf16x8s, ai);

        const bf16x8s* wp = (const bf16x8s*)(Wp + ((size_t)(wave * 4 + ks) * 16) * 64 + lane);
#pragma unroll
        for (int nf = 0; nf < 16; ++nf) {
            bf16x8s bf = wp[nf * 64];
            acc[nf] = __builtin_amdgcn_mfma_f32_16x16x32_bf16(bf, af, acc[nf], 0, 0, 0);
        }
    }

    // ---- multiply by prior (from registers) ----
#pragma unroll
    for (int nf = 0; nf < 16; ++nf) {
        acc[nf][0] *= pr[nf].x; acc[nf][1] *= pr[nf].y;
        acc[nf][2] *= pr[nf].z; acc[nf][3] *= pr[nf].w;
    }

    // ---- transpose through LDS (bf16, padded layout) ----
    __shared__ unsigned short ls[16][1032];   // 1032 = 1024 + 8 pad, 33 KB
#pragma unroll
    for (int nf = 0; nf < 16; ++nf) {
        uint2 hh;
        hh.x = cvt_pk_bf16(acc[nf][0], acc[nf][1]);
        hh.y = cvt_pk_bf16(acc[nf][2], acc[nf][3]);
        *(uint2*)&ls[q][wave * 256 + nf * 16 + 4 * g] = hh;
    }
    __syncthreads();

    // ---- load this wave's 4 rows: va[4][16], all static indices ----
    float va[4][16];
#pragma unroll
    for (int r = 0; r < 4; ++r) {
        const int row = wave * 4 + r;
#pragma unroll
        for (int j = 0; j < 4; ++j) {
            u16x4 hv = *(const u16x4*)&ls[row][j * 256 + lane * 4];
            va[r][j * 4 + 0] = bf2f(hv[0]);
            va[r][j * 4 + 1] = bf2f(hv[1]);
            va[r][j * 4 + 2] = bf2f(hv[2]);
            va[r][j * 4 + 3] = bf2f(hv[3]);
        }
    }

    // F(t), C(t) for 4 rows interleaved: S via fmax-form (VALU), count via
    // ballot+popc (SALU pipe), full-wave S reduce.
    auto eval4 = [&](const float t[4], float S[4], int C[4]) {
#pragma unroll
        for (int r = 0; r < 4; ++r) { S[r] = 0.f; C[r] = 0; }
#pragma unroll
        for (int e = 0; e < 16; ++e) {
#pragma unroll
            for (int r = 0; r < 4; ++r) {
                float d = va[r][e] - t[r];
                S[r] += fmaxf(d, 0.f);
                C[r] += (int)__popcll(__ballot(d > 0.f));
            }
        }
#pragma unroll
        for (int m = 1; m < 64; m <<= 1) {
#pragma unroll
            for (int r = 0; r < 4; ++r) S[r] += __shfl_xor(S[r], m);
        }
    };

    // ---- row maxima -> bracket [max-1, max] ----
    float mx[4];
#pragma unroll
    for (int r = 0; r < 4; ++r) {
        float m01 = fmaxf(va[r][0], va[r][1]),  m23 = fmaxf(va[r][2], va[r][3]);
        float m45 = fmaxf(va[r][4], va[r][5]),  m67 = fmaxf(va[r][6], va[r][7]);
        float m89 = fmaxf(va[r][8], va[r][9]),  mab = fmaxf(va[r][10], va[r][11]);
        float mcd = fmaxf(va[r][12], va[r][13]), mef = fmaxf(va[r][14], va[r][15]);
        mx[r] = fmaxf(fmaxf(fmaxf(m01, m23), fmaxf(m45, m67)),
                      fmaxf(fmaxf(m89, mab), fmaxf(mcd, mef)));
    }
#pragma unroll
    for (int m = 1; m < 64; m <<= 1) {
#pragma unroll
        for (int r = 0; r < 4; ++r) mx[r] = fmaxf(mx[r], __shfl_xor(mx[r], m));
    }

    float lo[4], hi[4], Flo[4];
    int Clo[4], Chi[4];
#pragma unroll
    for (int r = 0; r < 4; ++r) { lo[r] = mx[r] - 1.f; hi[r] = mx[r]; Chi[r] = 0; }
    eval4(lo, Flo, Clo);   // F(lo) >= 1 guaranteed

#pragma unroll 1
    for (int it = 0; it < 16; ++it) {
        bool all_done = true;
#pragma unroll
        for (int r = 0; r < 4; ++r) all_done = all_done && (Clo[r] == Chi[r]);
        if (all_done) break;
        float mid[4];
#pragma unroll
        for (int r = 0; r < 4; ++r) mid[r] = 0.5f * (lo[r] + hi[r]);
        float F[4]; int C[4];
        eval4(mid, F, C);
#pragma unroll
        for (int r = 0; r < 4; ++r) {
            if (F[r] >= 1.f) { lo[r] = mid[r]; Flo[r] = F[r]; Clo[r] = C[r]; }
            else             { hi[r] = mid[r]; Chi[r] = C[r]; }
        }
    }

    // segment-exact (or Newton-from-below, residual < 2^-16) finish
    float tau[4];
#pragma unroll
    for (int r = 0; r < 4; ++r)
        tau[r] = lo[r] + (Flo[r] - 1.f) * __builtin_amdgcn_rcpf((float)Clo[r]);

    // ---- output: reference sign convention -> relu(v + tau_std) ----
#pragma unroll
    for (int r = 0; r < 4; ++r) {
        const int row = wave * 4 + r;
        float* ob = out + (size_t)(r0 + row) * D_OUT + lane * 4;
#pragma unroll
        for (int j = 0; j < 4; ++j) {
            float4 o;
            o.x = fmaxf(va[r][j * 4 + 0] + tau[r], 0.f);
            o.y = fmaxf(va[r][j * 4 + 1] + tau[r], 0.f);
            o.z = fmaxf(va[r][j * 4 + 2] + tau[r], 0.f);
            o.w = fmaxf(va[r][j * 4 + 3] + tau[r], 0.f);
            *(float4*)(ob + j * 256) = o;
        }
    }
}

extern "C" void kernel_launch(void* const* d_in, const int* in_sizes, int n_in,
                              void* d_out, int out_size, void* d_ws, size_t ws_size,
                              hipStream_t stream) {
    const float* a     = (const float*)d_in[0];
    const float* prior = (const float*)d_in[1];
    const float* gamma = (const float*)d_in[2];
    const float* beta  = (const float*)d_in[3];
    const float* W     = (const float*)d_in[4];
    float* out = (float*)d_out;

    float* ss = (float*)d_ws;                            // 512 KB @ 0
    u16x8* Wp = (u16x8*)((char*)d_ws + 524288);          // 256 KB @ 512K

    gbn_stats_kernel<<<NCHUNK, VBS, 0, stream>>>(a, gamma, beta, ss);
    wpack_kernel<<<64, 256, 0, stream>>>(W, Wp);
    fused_kernel<<<B_ROWS / 16, 256, 0, stream>>>(a, prior, ss, Wp, out);
}